// Round 1
// baseline (85.960 us; speedup 1.0000x reference)
//
#include <hip/hip_runtime.h>
#include <math.h>

#define N_COMP 64

__global__ __launch_bounds__(256) void msg_eval_kernel(
    const float* __restrict__ lambdas,
    const float* __restrict__ kappas,
    const float* __restrict__ thetas,
    const float* __restrict__ phis,
    const float* __restrict__ wi,
    float* __restrict__ out,
    int n_dirs)
{
    // Per-component constants, computed redundantly per block (cheap: 64 threads,
    // a few transcendentals) to avoid a second kernel launch (~2 us in graph).
    __shared__ float4 s_c[N_COMP]; // (kx, ky, kz, kc) : exp2 argument coeffs, log2e-scaled
    __shared__ float  s_w[N_COMP]; // lambda_n * norm(kappa_n)

    const float M_INV_2PI = 0.15915494309189535f;
    const float M_INV_4PI = 0.07957747154594767f;
    const float LOG2E     = 1.4426950408889634f;

    const int tid = threadIdx.x;
    if (tid < N_COMP) {
        const float kappa = kappas[tid];
        const float theta = thetas[tid];
        const float phi   = phis[tid];
        const float st = sinf(theta);
        const float mux = st * cosf(phi);
        const float muy = st * sinf(phi);
        const float muz = cosf(theta);
        // normalization: kappa/(2pi(1-exp(-2k))), -> 1/4pi for tiny kappa
        const float k = fmaxf(kappa, 1e-8f);
        const float norm = (kappa < 1e-5f)
            ? M_INV_4PI
            : (k * M_INV_2PI) / (1.0f - expf(-2.0f * k));
        // pdf = norm * exp(kappa*(dot-1)) = norm * exp2(LOG2E*kappa*mux*wx + ... - LOG2E*kappa)
        s_c[tid] = make_float4(kappa * mux * LOG2E,
                               kappa * muy * LOG2E,
                               kappa * muz * LOG2E,
                               -kappa * LOG2E);
        s_w[tid] = lambdas[tid] * norm;
    }
    __syncthreads();

    // Each thread handles 4 consecutive directions: 12 floats = 3 float4 loads
    // (fully vectorized, 48 B/thread; cache serves the 48 B-stride pattern).
    const int gtid = blockIdx.x * blockDim.x + tid;
    const int i0 = 4 * gtid;
    if (i0 + 3 < n_dirs) {
        const float4* wi4 = (const float4*)wi;
        const float4 f0 = wi4[3 * gtid + 0];
        const float4 f1 = wi4[3 * gtid + 1];
        const float4 f2 = wi4[3 * gtid + 2];
        const float x0 = f0.x, y0 = f0.y, z0 = f0.z;
        const float x1 = f0.w, y1 = f1.x, z1 = f1.y;
        const float x2 = f1.z, y2 = f1.w, z2 = f2.x;
        const float x3 = f2.y, y3 = f2.z, z3 = f2.w;

        float a0 = 0.f, a1 = 0.f, a2 = 0.f, a3 = 0.f;
        #pragma unroll 16
        for (int n = 0; n < N_COMP; ++n) {
            const float4 c = s_c[n];   // ds_read_b128 broadcast
            const float wn = s_w[n];   // ds_read_b32 broadcast
            const float e0 = __builtin_amdgcn_exp2f(fmaf(c.x, x0, fmaf(c.y, y0, fmaf(c.z, z0, c.w))));
            const float e1 = __builtin_amdgcn_exp2f(fmaf(c.x, x1, fmaf(c.y, y1, fmaf(c.z, z1, c.w))));
            const float e2 = __builtin_amdgcn_exp2f(fmaf(c.x, x2, fmaf(c.y, y2, fmaf(c.z, z2, c.w))));
            const float e3 = __builtin_amdgcn_exp2f(fmaf(c.x, x3, fmaf(c.y, y3, fmaf(c.z, z3, c.w))));
            a0 = fmaf(wn, e0, a0);
            a1 = fmaf(wn, e1, a1);
            a2 = fmaf(wn, e2, a2);
            a3 = fmaf(wn, e3, a3);
        }
        ((float4*)out)[gtid] = make_float4(a0, a1, a2, a3);
    } else if (i0 < n_dirs) {
        // tail (not hit for n_dirs = 2^20, kept for generality)
        for (int i = i0; i < n_dirs; ++i) {
            const float x = wi[3 * i], y = wi[3 * i + 1], z = wi[3 * i + 2];
            float a = 0.f;
            for (int n = 0; n < N_COMP; ++n) {
                const float4 c = s_c[n];
                a = fmaf(s_w[n],
                         __builtin_amdgcn_exp2f(fmaf(c.x, x, fmaf(c.y, y, fmaf(c.z, z, c.w)))),
                         a);
            }
            out[i] = a;
        }
    }
}

extern "C" void kernel_launch(void* const* d_in, const int* in_sizes, int n_in,
                              void* d_out, int out_size, void* d_ws, size_t ws_size,
                              hipStream_t stream) {
    const float* lambdas = (const float*)d_in[0];
    const float* kappas  = (const float*)d_in[1];
    const float* thetas  = (const float*)d_in[2];
    const float* phis    = (const float*)d_in[3];
    const float* wi      = (const float*)d_in[4];
    float* out = (float*)d_out;

    const int n_dirs = in_sizes[4] / 3;            // 1048576
    const int n_groups = (n_dirs + 3) / 4;         // 4 dirs per thread
    const int block = 256;
    const int grid = (n_groups + block - 1) / block;

    msg_eval_kernel<<<grid, block, 0, stream>>>(lambdas, kappas, thetas, phis, wi, out, n_dirs);
}

// Round 2
// 84.131 us; speedup vs baseline: 1.0217x; 1.0217x over previous
//
#include <hip/hip_runtime.h>
#include <math.h>

#define N_COMP 64

typedef float v2f __attribute__((ext_vector_type(2)));

__global__ __launch_bounds__(256) void msg_eval_kernel(
    const float* __restrict__ lambdas,
    const float* __restrict__ kappas,
    const float* __restrict__ thetas,
    const float* __restrict__ phis,
    const float* __restrict__ wi,
    float* __restrict__ out,
    int n_dirs)
{
    // Per-component constants (cx, cy, cz, w') with:
    //   cx,cy,cz = kappa * mu * log2(e)          (exp2-domain dot coefficients)
    //   w'       = lambda * norm(kappa) * 2^(-kappa*log2(e))   (bias folded in)
    // so per (dir, comp): pdf*lambda = w' * exp2(cx*x + cy*y + cz*z).
    __shared__ float4 s_c[N_COMP];

    const float M_INV_2PI = 0.15915494309189535f;
    const float M_INV_4PI = 0.07957747154594767f;
    const float LOG2E     = 1.4426950408889634f;

    const int tid = threadIdx.x;
    if (tid < N_COMP) {
        const float kappa = kappas[tid];
        const float theta = thetas[tid];
        const float phi   = phis[tid];
        const float st = sinf(theta);
        const float mux = st * cosf(phi);
        const float muy = st * sinf(phi);
        const float muz = cosf(theta);
        const float k = fmaxf(kappa, 1e-8f);
        const float norm = (kappa < 1e-5f)
            ? M_INV_4PI
            : (k * M_INV_2PI) / (1.0f - __builtin_amdgcn_exp2f(-2.0f * k * LOG2E));
        const float kl = kappa * LOG2E;
        s_c[tid] = make_float4(kl * mux, kl * muy, kl * muz,
                               lambdas[tid] * norm * __builtin_amdgcn_exp2f(-kl));
    }
    __syncthreads();

    const int gtid = blockIdx.x * blockDim.x + tid;
    const int i0 = 4 * gtid;
    if (i0 + 3 < n_dirs) {
        const float4* wi4 = (const float4*)wi;
        const float4 f0 = wi4[3 * gtid + 0];
        const float4 f1 = wi4[3 * gtid + 1];
        const float4 f2 = wi4[3 * gtid + 2];
        // dirs 0..3 packed pairwise for v_pk_fma_f32
        const v2f X01 = {f0.x, f0.w}, Y01 = {f0.y, f1.x}, Z01 = {f0.z, f1.y};
        const v2f X23 = {f1.z, f2.y}, Y23 = {f1.w, f2.z}, Z23 = {f2.x, f2.w};

        v2f a01 = {0.f, 0.f}, a23 = {0.f, 0.f};
        #pragma unroll 8
        for (int n = 0; n < N_COMP; ++n) {
            const float4 c = s_c[n];         // single ds_read_b128 broadcast
            const v2f cx = {c.x, c.x}, cy = {c.y, c.y}, cz = {c.z, c.z};
            const v2f w2 = {c.w, c.w};
            const v2f arg01 = __builtin_elementwise_fma(cx, X01,
                              __builtin_elementwise_fma(cy, Y01, cz * Z01));
            const v2f arg23 = __builtin_elementwise_fma(cx, X23,
                              __builtin_elementwise_fma(cy, Y23, cz * Z23));
            const v2f e01 = {__builtin_amdgcn_exp2f(arg01.x), __builtin_amdgcn_exp2f(arg01.y)};
            const v2f e23 = {__builtin_amdgcn_exp2f(arg23.x), __builtin_amdgcn_exp2f(arg23.y)};
            a01 = __builtin_elementwise_fma(w2, e01, a01);
            a23 = __builtin_elementwise_fma(w2, e23, a23);
        }
        ((float4*)out)[gtid] = make_float4(a01.x, a01.y, a23.x, a23.y);
    } else if (i0 < n_dirs) {
        for (int i = i0; i < n_dirs; ++i) {
            const float x = wi[3 * i], y = wi[3 * i + 1], z = wi[3 * i + 2];
            float a = 0.f;
            for (int n = 0; n < N_COMP; ++n) {
                const float4 c = s_c[n];
                a = fmaf(c.w,
                         __builtin_amdgcn_exp2f(fmaf(c.x, x, fmaf(c.y, y, c.z * z))),
                         a);
            }
            out[i] = a;
        }
    }
}

extern "C" void kernel_launch(void* const* d_in, const int* in_sizes, int n_in,
                              void* d_out, int out_size, void* d_ws, size_t ws_size,
                              hipStream_t stream) {
    const float* lambdas = (const float*)d_in[0];
    const float* kappas  = (const float*)d_in[1];
    const float* thetas  = (const float*)d_in[2];
    const float* phis    = (const float*)d_in[3];
    const float* wi      = (const float*)d_in[4];
    float* out = (float*)d_out;

    const int n_dirs = in_sizes[4] / 3;            // 1048576
    const int n_groups = (n_dirs + 3) / 4;         // 4 dirs per thread
    const int block = 256;
    const int grid = (n_groups + block - 1) / block;

    msg_eval_kernel<<<grid, block, 0, stream>>>(lambdas, kappas, thetas, phis, wi, out, n_dirs);
}